// Round 9
// baseline (52.982 us; speedup 1.0000x reference)
//
#include <hip/hip_runtime.h>

// SpikingLinear: 40-step LIF scan over sparse one-shot input spikes.
// R9: parallelize the in-block sort (R8 used 64/256 threads + a 64-deep
// serial scan; now 128 hist threads x 16 elems, 160 scan workers x 32-chains,
// 128 scatter threads -- R4's validated 3-level scheme). ordl content is
// element-identical (j-ascending per bin) -> bit-exact. Main loop/transpose
// unchanged: isolates "sort overhead" vs "scattered-L2 ceiling" attribution.
//
// Workspace: WT only: (IN_DIM+1) x OUT_DIM f32 = 16.78 MB (row 2048 = zeros).

#define IN_DIM   2048
#define OUT_DIM  2048
#define BATCH    256
#define STEPS    40
#define ROWBYTES (OUT_DIM * 4)
#define HS       41            // hist row stride (ints) -> no bank conflicts
#define ORD_CAP  2176          // 2048 + 40*3 pad, rounded to x4 (16B quads)

// ---- transpose W[O][IN] -> WT[IN][O]; o-tile 'by' on XCD by%8 (= id%8) ----
__global__ __launch_bounds__(256) void transpose_k(const float* __restrict__ W,
                                                   float* __restrict__ WT) {
    __shared__ float tile[64][65];
    const int id = blockIdx.x;
    const int by = id & 31;        // o-tile (fast-varying -> XCD = by%8)
    const int bx = id >> 5;        // j-tile
    const int x  = threadIdx.x & 63;
    const int y4 = threadIdx.x >> 6;
#pragma unroll
    for (int i = 0; i < 16; ++i) {
        const int a = y4 * 16 + i;     // o-local
        tile[a][x] = W[(size_t)(by * 64 + a) * IN_DIM + (bx * 64 + x)];
    }
    if (bx == 0 && y4 == 0)            // zero sentinel row (row IN_DIM)
        WT[(size_t)IN_DIM * OUT_DIM + by * 64 + x] = 0.0f;
    __syncthreads();
#pragma unroll
    for (int i = 0; i < 16; ++i) {
        const int r = y4 * 16 + i;     // j-local
        WT[(size_t)(bx * 64 + r) * OUT_DIM + (by * 64 + x)] = tile[x][r];
    }
}

// ---- snn: block (b, sg): sort row b in LDS (256-thr parallel), then 4
//      waves run slices s = sg + w*8 (all on XCD sg = transpose's writer) ----
__global__ __launch_bounds__(256) void snn_k(const float* __restrict__ WT,
                                             const float* __restrict__ inp,
                                             float* __restrict__ out) {
    __shared__ int hist[128 * HS];               // 20992 B
    __shared__ int chunkcnt[STEPS * 4];
    __shared__ int bs[STEPS + 1];                // padded bucket starts
    __shared__ int tot[STEPS];                   // true bucket sizes
    __shared__ __align__(16) int ordl[ORD_CAP];  // bucket-sorted byte row-offsets

    const int bid = blockIdx.x;
    const int sg  = bid & 7;        // slice group == XCD (round-robin dispatch)
    const int b   = bid >> 3;
    const int t   = threadIdx.x;

    // phase 1: zero hist
    for (int i = t; i < 128 * HS; i += 256) hist[i] = 0;
    __syncthreads();

    // phase 2: threads 0..127 load row b (16 elems each) + private histogram
    int ks[16];
    if (t < 128) {
        const float* row = inp + (size_t)b * IN_DIM + t * 16;
#pragma unroll
        for (int i = 0; i < 4; ++i) {
            const float4 v = *(const float4*)(row + i * 4);  // t=step*0.5 exact
            ks[i * 4 + 0] = (int)(v.x * 2.0f);
            ks[i * 4 + 1] = (int)(v.y * 2.0f);
            ks[i * 4 + 2] = (int)(v.z * 2.0f);
            ks[i * 4 + 3] = (int)(v.w * 2.0f);
        }
#pragma unroll
        for (int i = 0; i < 16; ++i) ++hist[t * HS + ks[i]];
    }
    __syncthreads();

    // phase 3a: 160 workers: worker (k,q) sums chunk q (32 thread-rows) of bin k
    if (t < STEPS * 4) {
        const int k = t >> 2, q = t & 3;
        int run = 0;
#pragma unroll
        for (int i = 0; i < 32; i += 8) {
            const int base = (q * 32 + i) * HS + k;
            const int c0 = hist[base + 0 * HS], c1 = hist[base + 1 * HS];
            const int c2 = hist[base + 2 * HS], c3 = hist[base + 3 * HS];
            const int c4 = hist[base + 4 * HS], c5 = hist[base + 5 * HS];
            const int c6 = hist[base + 6 * HS], c7 = hist[base + 7 * HS];
            run += ((c0 + c1) + (c2 + c3)) + ((c4 + c5) + (c6 + c7));
        }
        chunkcnt[k * 4 + q] = run;
    }
    __syncthreads();

    // phase 3b: padded bucket starts (serial over 40 bins, trivial)
    if (t == 0) {
        int run = 0;
        for (int k = 0; k < STEPS; ++k) {
            bs[k] = run;
            const int tk = (chunkcnt[k * 4] + chunkcnt[k * 4 + 1]) +
                           (chunkcnt[k * 4 + 2] + chunkcnt[k * 4 + 3]);
            tot[k] = tk;
            run += (tk + 3) & ~3;
        }
        bs[STEPS] = run;
    }
    __syncthreads();

    // phase 3c: rewrite chunks as global exclusive prefixes (bs folded in)
    if (t < STEPS * 4) {
        const int k = t >> 2, q = t & 3;
        int run = bs[k];
        for (int qq = 0; qq < q; ++qq) run += chunkcnt[k * 4 + qq];
#pragma unroll 8
        for (int i = 0; i < 32; ++i) {
            const int a = (q * 32 + i) * HS + k;
            const int c = hist[a];
            hist[a] = run;
            run += c;
        }
    }
    __syncthreads();

    // phase 4: scatter (threads 0..127, ascending j within bin -> exact
    // reference sum order) + sentinel padding (threads 128..167)
    if (t < 128) {
#pragma unroll
        for (int i = 0; i < 16; ++i) {
            const int k = ks[i];
            const int pos = hist[t * HS + k]++;
            ordl[pos] = (t * 16 + i) * ROWBYTES;
        }
    } else if (t < 128 + STEPS) {
        const int k = t - 128;
        for (int p2 = bs[k] + tot[k]; p2 < bs[k + 1]; ++p2)
            ordl[p2] = IN_DIM * ROWBYTES;      // +0.0f, exact
    }
    __syncthreads();

    // ---- main LIF loop: wave w handles slice s = sg + w*8 ----
    const int wave = t >> 6, lane = t & 63;
    const int s    = sg + wave * 8;
    const char* wb = (const char*)WT + ((s * 64 + lane) << 2);

    float I = 0.f, V = 0.f;
    int   f = 0;
    int   p = 0;
    for (int k = 0; k < STEPS; ++k) {
        const int e = bs[k + 1];
        float a = 0.f;
        // unroll x8: 8 row loads in flight (indices from LDS broadcast)
        for (; p + 8 <= e; p += 8) {
            const int4 ja = *(const int4*)(ordl + p);
            const int4 jb = *(const int4*)(ordl + p + 4);
            const float w0 = *(const float*)(wb + ja.x);
            const float w1 = *(const float*)(wb + ja.y);
            const float w2 = *(const float*)(wb + ja.z);
            const float w3 = *(const float*)(wb + ja.w);
            const float w4 = *(const float*)(wb + jb.x);
            const float w5 = *(const float*)(wb + jb.y);
            const float w6 = *(const float*)(wb + jb.z);
            const float w7 = *(const float*)(wb + jb.w);
            // sequential adds, ascending j: same order as validated R4 kernel
            a = (((((((((a + w0) + w1) + w2) + w3) + w4) + w5) + w6) + w7));
        }
        if (p < e) {   // exactly one remaining quad (buckets padded to x4)
            const int4 ja = *(const int4*)(ordl + p);
            p += 4;
            const float w0 = *(const float*)(wb + ja.x);
            const float w1 = *(const float*)(wb + ja.y);
            const float w2 = *(const float*)(wb + ja.z);
            const float w3 = *(const float*)(wb + ja.w);
            a = ((((a + w0) + w1) + w2) + w3);
        }
        // V uses I from previous step, then I update, then spike (ref order)
        V += 0.025f * (I - V);
        I = 0.9f * I + a;
        if (V > 1.0f) { if (f == 0) f = k; V = 0.f; }
        if (__all(f != 0)) break;    // per-wave exit, no block barrier needed
    }
    out[(size_t)b * OUT_DIM + s * 64 + lane] = f ? (float)f : 20.0f;
}

extern "C" void kernel_launch(void* const* d_in, const int* in_sizes, int n_in,
                              void* d_out, int out_size, void* d_ws, size_t ws_size,
                              hipStream_t stream) {
    const float* inp = (const float*)d_in[0];
    const float* W   = (const float*)d_in[1];
    float* out = (float*)d_out;
    float* WT  = (float*)d_ws;    // (IN_DIM+1) x OUT_DIM

    transpose_k<<<(IN_DIM / 64) * (OUT_DIM / 64), 256, 0, stream>>>(W, WT);
    snn_k<<<BATCH * 8, 256, 0, stream>>>(WT, inp, out);
}

// Round 10
// 42.977 us; speedup vs baseline: 1.2328x; 1.2328x over previous
//
#include <hip/hip_runtime.h>

// SpikingLinear: 40-step LIF scan over sparse one-shot input spikes.
// R10: revert sort to R8's conflict-free scheme (R9's 160-worker scan had
// (q*32*41 % 32)==0 bank aliasing -> 4.6M conflicts, -10us). New single
// variable: XOR L2-channel swizzle of WT -- row j's slice-s 256B chunk lives
// at byte ((s ^ (j&31))<<8) so address bits [8:12] vary per row instead of
// being constant per wave (suspected L2 channel imbalance at 21 TB/s).
// ordl stores j*8192 + ((j&31)<<8); wave XORs wave-uniform (s<<8). Values
// and sum order bit-identical to R8.
//
// Workspace: WT only: (IN_DIM+1) x OUT_DIM f32 = 16.78 MB (row 2048 = zeros).

#define IN_DIM   2048
#define OUT_DIM  2048
#define BATCH    256
#define STEPS    40
#define ROWBYTES (OUT_DIM * 4)
#define HS       41            // hist row stride (ints) -> no bank conflicts
#define ORD_CAP  2176          // 2048 + 40*3 pad, rounded to x4 (16B quads)

// ---- transpose W[O][IN] -> WT[IN][O], chunk-swizzled; o-tile by on XCD by%8 --
__global__ __launch_bounds__(256) void transpose_k(const float* __restrict__ W,
                                                   float* __restrict__ WT) {
    __shared__ float tile[64][65];
    const int id = blockIdx.x;
    const int by = id & 31;        // o-tile == slice (fast-varying -> XCD = by%8)
    const int bx = id >> 5;        // j-tile
    const int x  = threadIdx.x & 63;
    const int y4 = threadIdx.x >> 6;
#pragma unroll
    for (int i = 0; i < 16; ++i) {
        const int a = y4 * 16 + i;     // o-local
        tile[a][x] = W[(size_t)(by * 64 + a) * IN_DIM + (bx * 64 + x)];
    }
    if (bx == 0 && y4 == 0)            // zero sentinel row (row IN_DIM, all 8KB)
        WT[(size_t)IN_DIM * OUT_DIM + by * 64 + x] = 0.0f;
    __syncthreads();
#pragma unroll
    for (int i = 0; i < 16; ++i) {
        const int r = y4 * 16 + i;     // j-local
        const int row = bx * 64 + r;   // global j
        // swizzled chunk: slice 'by' of row j at byte ((by ^ (j&31))<<8)
        float* dst = (float*)((char*)WT + (size_t)row * ROWBYTES
                              + ((by ^ (row & 31)) << 8));
        dst[x] = tile[x][r];
    }
}

// ---- snn: block (b, sg): R8 LDS sort, then 4 waves run slices sg + w*8 ----
__global__ __launch_bounds__(256) void snn_k(const float* __restrict__ WT,
                                             const float* __restrict__ inp,
                                             float* __restrict__ out) {
    __shared__ __align__(16) int ordl[ORD_CAP];  // bucket-sorted swizzled offsets
    __shared__ int hist[64 * HS];
    __shared__ int bs[STEPS + 1];                // padded bucket starts
    __shared__ int tot[STEPS];                   // true bucket sizes

    const int bid = blockIdx.x;
    const int sg  = bid & 7;        // slice group == XCD (round-robin dispatch)
    const int b   = bid >> 3;
    const int t   = threadIdx.x;

    // phase 1: zero hist
    for (int i = t; i < 64 * HS; i += 256) hist[i] = 0;
    __syncthreads();

    // phase 2: threads 0..63 load row b (32 elems each) + private histogram
    int ks[32];
    if (t < 64) {
        const float* row = inp + (size_t)b * IN_DIM + t * 32;
#pragma unroll
        for (int i = 0; i < 8; ++i) {
            const float4 v = *(const float4*)(row + i * 4);  // t=step*0.5 exact
            ks[i * 4 + 0] = (int)(v.x * 2.0f);
            ks[i * 4 + 1] = (int)(v.y * 2.0f);
            ks[i * 4 + 2] = (int)(v.z * 2.0f);
            ks[i * 4 + 3] = (int)(v.w * 2.0f);
        }
#pragma unroll
        for (int i = 0; i < 32; ++i) ++hist[t * HS + ks[i]];
    }
    __syncthreads();

    // phase 3: threads 0..39: exclusive prefix over the 64 thread-rows of bin t
    if (t < STEPS) {
        int run = 0;
        for (int tt = 0; tt < 64; ++tt) {
            const int c = hist[tt * HS + t];
            hist[tt * HS + t] = run;
            run += c;
        }
        tot[t] = run;
    }
    __syncthreads();

    // phase 4: padded bucket starts (serial over 40 bins, trivial)
    if (t == 0) {
        int run = 0;
        for (int k = 0; k < STEPS; ++k) {
            bs[k] = run;
            run += (tot[k] + 3) & ~3;
        }
        bs[STEPS] = run;
    }
    __syncthreads();

    // phase 5: scatter (threads 0..63, ascending j within bin -> exact
    // reference sum order) + sentinel padding (threads 64..103)
    if (t < 64) {
#pragma unroll
        for (int i = 0; i < 32; ++i) {
            const int k = ks[i];
            const int pos = bs[k] + hist[t * HS + k]++;
            const int j = t * 32 + i;
            ordl[pos] = j * ROWBYTES + ((j & 31) << 8);   // swizzled offset
        }
    } else if (t < 64 + STEPS) {
        const int k = t - 64;
        for (int p2 = bs[k] + tot[k]; p2 < bs[k + 1]; ++p2)
            ordl[p2] = IN_DIM * ROWBYTES;   // (2048&31)==0 -> chunk s of zero row
    }
    __syncthreads();

    // ---- main LIF loop: wave w handles slice s = sg + w*8 ----
    const int wave = t >> 6, lane = t & 63;
    const int s    = sg + wave * 8;
    const int sx   = s << 8;                       // wave-uniform XOR key
    const char* wb = (const char*)WT + (lane << 2);

    float I = 0.f, V = 0.f;
    int   f = 0;
    int   p = 0;
    for (int k = 0; k < STEPS; ++k) {
        const int e = bs[k + 1];
        float a = 0.f;
        // unroll x8: 8 row loads in flight (indices from LDS broadcast)
        for (; p + 8 <= e; p += 8) {
            const int4 ja = *(const int4*)(ordl + p);
            const int4 jb = *(const int4*)(ordl + p + 4);
            const float w0 = *(const float*)(wb + (ja.x ^ sx));
            const float w1 = *(const float*)(wb + (ja.y ^ sx));
            const float w2 = *(const float*)(wb + (ja.z ^ sx));
            const float w3 = *(const float*)(wb + (ja.w ^ sx));
            const float w4 = *(const float*)(wb + (jb.x ^ sx));
            const float w5 = *(const float*)(wb + (jb.y ^ sx));
            const float w6 = *(const float*)(wb + (jb.z ^ sx));
            const float w7 = *(const float*)(wb + (jb.w ^ sx));
            // sequential adds, ascending j: same order as validated R4/R8
            a = (((((((((a + w0) + w1) + w2) + w3) + w4) + w5) + w6) + w7));
        }
        if (p < e) {   // exactly one remaining quad (buckets padded to x4)
            const int4 ja = *(const int4*)(ordl + p);
            p += 4;
            const float w0 = *(const float*)(wb + (ja.x ^ sx));
            const float w1 = *(const float*)(wb + (ja.y ^ sx));
            const float w2 = *(const float*)(wb + (ja.z ^ sx));
            const float w3 = *(const float*)(wb + (ja.w ^ sx));
            a = ((((a + w0) + w1) + w2) + w3);
        }
        // V uses I from previous step, then I update, then spike (ref order)
        V += 0.025f * (I - V);
        I = 0.9f * I + a;
        if (V > 1.0f) { if (f == 0) f = k; V = 0.f; }
        if (__all(f != 0)) break;    // per-wave exit, no block barrier needed
    }
    out[(size_t)b * OUT_DIM + s * 64 + lane] = f ? (float)f : 20.0f;
}

extern "C" void kernel_launch(void* const* d_in, const int* in_sizes, int n_in,
                              void* d_out, int out_size, void* d_ws, size_t ws_size,
                              hipStream_t stream) {
    const float* inp = (const float*)d_in[0];
    const float* W   = (const float*)d_in[1];
    float* out = (float*)d_out;
    float* WT  = (float*)d_ws;    // (IN_DIM+1) x OUT_DIM, chunk-swizzled

    transpose_k<<<(IN_DIM / 64) * (OUT_DIM / 64), 256, 0, stream>>>(W, WT);
    snn_k<<<BATCH * 8, 256, 0, stream>>>(WT, inp, out);
}